// Round 4
// baseline (731.610 us; speedup 1.0000x reference)
//
#include <hip/hip_runtime.h>
#include <hip/hip_bf16.h>

#define N_TOK 4096
#define H_DIM 2048
#define I_DIM 1408
#define E_NUM 8
#define CAP   1280

typedef __hip_bfloat16 bf16;
typedef unsigned short us;
typedef __bf16 bf16x8 __attribute__((ext_vector_type(8)));
typedef float f32x4 __attribute__((ext_vector_type(4)));

__device__ inline void gld_lds16(const void* g, void* l) {
    __builtin_amdgcn_global_load_lds((const __attribute__((address_space(1))) void*)g,
                                     (__attribute__((address_space(3))) void*)l,
                                     16, 0, 0);
}

// load 8 fp32 from global, convert to bf16, one ds_write_b128
__device__ inline void stage_f32(const float* __restrict__ src, us* dst) {
    float4 a = *(const float4*)src;
    float4 b = *(const float4*)(src + 4);
    union { us u[8]; uint4 q; } o;
    float f[8] = {a.x, a.y, a.z, a.w, b.x, b.y, b.z, b.w};
#pragma unroll
    for (int j = 0; j < 8; j++) {
        bf16 v = __float2bfloat16(f[j]);
        o.u[j] = *(us*)&v;
    }
    *(uint4*)dst = o.q;
}

// ---------------- fp32 -> bf16 conversion (x only), 8 elems/thread ----------------
__global__ void cvt8(const float* __restrict__ s, us* __restrict__ d, long n) {
    long i = ((long)blockIdx.x * blockDim.x + threadIdx.x) * 8;
    if (i >= n) return;
    float4 v0 = *(const float4*)(s + i);
    float4 v1 = *(const float4*)(s + i + 4);
    union { us u[8]; uint4 q; } o;
    float f[8] = {v0.x, v0.y, v0.z, v0.w, v1.x, v1.y, v1.z, v1.w};
#pragma unroll
    for (int j = 0; j < 8; j++) {
        bf16 b = __float2bfloat16(f[j]);
        o.u[j] = *(us*)&b;
    }
    *(uint4*)(d + i) = o.q;
}

// ---------------- router ----------------
__global__ void router_k(const float* __restrict__ x, const float* __restrict__ Wr,
                         float* __restrict__ top_val, int* __restrict__ top_idx) {
    int tok  = (blockIdx.x * blockDim.x + threadIdx.x) >> 6;
    int lane = threadIdx.x & 63;
    if (tok >= N_TOK) return;
    const float* xr = x + (size_t)tok * H_DIM;
    float acc[E_NUM];
#pragma unroll
    for (int e = 0; e < E_NUM; e++) acc[e] = 0.f;
    for (int h = lane; h < H_DIM; h += 64) {
        float xv = xr[h];
#pragma unroll
        for (int e = 0; e < E_NUM; e++) acc[e] += xv * Wr[e * H_DIM + h];
    }
#pragma unroll
    for (int e = 0; e < E_NUM; e++) {
#pragma unroll
        for (int off = 32; off > 0; off >>= 1) acc[e] += __shfl_xor(acc[e], off, 64);
    }
    if (lane == 0) {
        float mx = acc[0];
#pragma unroll
        for (int e = 1; e < E_NUM; e++) mx = fmaxf(mx, acc[e]);
        float p[E_NUM], s = 0.f;
#pragma unroll
        for (int e = 0; e < E_NUM; e++) { p[e] = __expf(acc[e] - mx); s += p[e]; }
        float inv = 1.f / s;
#pragma unroll
        for (int e = 0; e < E_NUM; e++) p[e] *= inv;
        int i0 = 0;
#pragma unroll
        for (int e = 1; e < E_NUM; e++) if (p[e] > p[i0]) i0 = e;
        int i1 = -1;
#pragma unroll
        for (int e = 0; e < E_NUM; e++) {
            if (e == i0) continue;
            if (i1 < 0 || p[e] > p[i1]) i1 = e;
        }
        top_idx[tok * 2]     = i0;
        top_idx[tok * 2 + 1] = i1;
        top_val[tok * 2]     = p[i0];
        top_val[tok * 2 + 1] = p[i1];
    }
}

// ---------------- capacity assignment (+ token->slot map for combine) ----------------
__global__ void assign_k(const int* __restrict__ top_idx, const float* __restrict__ top_val,
                         int* __restrict__ toklist, int* __restrict__ pos,
                         float* __restrict__ wz, int* __restrict__ counts) {
    const int T = 256;
    const int CH = (2 * N_TOK) / T; // 32
    int t = threadIdx.x;
    for (int i = t; i < E_NUM * CAP; i += T) toklist[i] = N_TOK;
    __shared__ int cnt[T][E_NUM];
    int local[E_NUM];
#pragma unroll
    for (int e = 0; e < E_NUM; e++) local[e] = 0;
    for (int q = 0; q < CH; q++) {
        int j = t * CH + q;
        int slot = j >> 12;
        int tok  = j & 4095;
        int e = top_idx[tok * 2 + slot];
        local[e]++;
    }
#pragma unroll
    for (int e = 0; e < E_NUM; e++) cnt[t][e] = local[e];
    __syncthreads();
    if (t < E_NUM) {
        int run = 0;
        for (int i = 0; i < T; i++) { int c = cnt[i][t]; cnt[i][t] = run; run += c; }
        counts[t] = run < CAP ? run : CAP;
    }
    __syncthreads();
    int run[E_NUM];
#pragma unroll
    for (int e = 0; e < E_NUM; e++) run[e] = cnt[t][e];
    for (int q = 0; q < CH; q++) {
        int j = t * CH + q;
        int slot = j >> 12;
        int tok  = j & 4095;
        int e = top_idx[tok * 2 + slot];
        int rank = ++run[e];
        if (rank <= CAP) {
            toklist[e * CAP + rank - 1] = tok;
            pos[tok * 2 + slot] = e * CAP + rank - 1;
            wz[tok * 2 + slot]  = top_val[tok * 2 + slot];
        } else {
            pos[tok * 2 + slot] = -1;
            wz[tok * 2 + slot]  = 0.f;
        }
    }
}

// ---------------- fused gate+up GEMM + SwiGLU ----------------
// Weights read DIRECTLY as fp32, converted in-register while staging to LDS
// (no pre-conversion pass). Balanced XCD-group schedule: flat block id d ->
// XCD d&7 (hardware round-robin); within one XCD's stream the 10 m-blocks of
// one (e,n) weight panel are consecutive -> panel fetched into ONE L2, once.
// Groups dealt round-robin over XCDs -> every XCD gets a uniform expert mix
// (fixes R2's counts[e] imbalance). A-panels are L3-resident (33.5 MB).
__global__ __launch_bounds__(256, 3)
void gu_fused(const us* __restrict__ A, const float* __restrict__ Wg,
              const float* __restrict__ Wu, us* __restrict__ hbuf,
              const int* __restrict__ toklist, const int* __restrict__ counts) {
    const int MT = CAP / 128;       // 10
    const int NT = I_DIM / 128;     // 11
    const int d   = blockIdx.x;
    const int xcd = d & 7;
    const int sub = d >> 3;
    const int m0  = (sub % MT) * 128;     // m fastest within group
    const int g   = (sub / MT) * 8 + xcd; // group id = (e,n)
    const int e   = g / NT;
    const int n0  = (g % NT) * 128;
    if (m0 >= counts[e]) return;

    __shared__ us As[128 * 64];   // two sub-buffers of [128][32]
    __shared__ us Bg[128 * 64];
    __shared__ us Bu[128 * 64];

    const int t  = threadIdx.x;
    const int r0 = t >> 2;          // 0..63
    const int c8 = (t & 3) * 8;     // 0/8/16/24

    int tok0 = toklist[e * CAP + m0 + r0];
    int tok1 = toklist[e * CAP + m0 + r0 + 64];
    const us* aP0 = A + (size_t)tok0 * H_DIM + c8;
    const us* aP1 = A + (size_t)tok1 * H_DIM + c8;
    const float* gP0 = Wg + ((size_t)e * I_DIM + n0 + r0) * H_DIM + c8;
    const float* gP1 = gP0 + (size_t)64 * H_DIM;
    const float* uP0 = Wu + ((size_t)e * I_DIM + n0 + r0) * H_DIM + c8;
    const float* uP1 = uP0 + (size_t)64 * H_DIM;

    us* lA0 = As + t * 8;  us* lA1 = lA0 + 64 * 32;   // sub0 rows 0-63 / 64-127
    us* lG0 = Bg + t * 8;  us* lG1 = lG0 + 64 * 32;
    us* lU0 = Bu + t * 8;  us* lU1 = lU0 + 64 * 32;

    const int lane = t & 63;
    const int wave = t >> 6;
    const int wm   = (wave & 1) * 64;
    const int wn   = (wave >> 1) * 64;
    const int l15  = lane & 15;
    const int quad = lane >> 4;

    f32x4 ag[4][4], au[4][4];
#pragma unroll
    for (int i = 0; i < 4; i++)
#pragma unroll
        for (int j = 0; j < 4; j++) {
            ag[i][j] = (f32x4){0.f, 0.f, 0.f, 0.f};
            au[i][j] = (f32x4){0.f, 0.f, 0.f, 0.f};
        }

    for (int k = 0; k < H_DIM; k += 64) {
        // A: async direct-to-LDS (bf16 already)
        gld_lds16(aP0,      lA0);
        gld_lds16(aP1,      lA1);
        gld_lds16(aP0 + 32, lA0 + 4096);
        gld_lds16(aP1 + 32, lA1 + 4096);
        // B: fp32 -> bf16 reg-staged (same LDS layout as the gld path)
        stage_f32(gP0,             lG0);
        stage_f32(gP1,             lG1);
        stage_f32(gP0 + 32,        lG0 + 4096);
        stage_f32(gP1 + 32,        lG1 + 4096);
        stage_f32(uP0,             lU0);
        stage_f32(uP1,             lU1);
        stage_f32(uP0 + 32,        lU0 + 4096);
        stage_f32(uP1 + 32,        lU1 + 4096);
        aP0 += 64; aP1 += 64; gP0 += 64; gP1 += 64; uP0 += 64; uP1 += 64;
        __syncthreads();
#pragma unroll
        for (int kk = 0; kk < 2; kk++) {
            bf16x8 af[4];
#pragma unroll
            for (int i = 0; i < 4; i++)
                af[i] = *(const bf16x8*)(As + kk * 4096 + (wm + i * 16 + l15) * 32 + quad * 8);
            {
                bf16x8 bfr[4];
#pragma unroll
                for (int j = 0; j < 4; j++)
                    bfr[j] = *(const bf16x8*)(Bg + kk * 4096 + (wn + j * 16 + l15) * 32 + quad * 8);
#pragma unroll
                for (int i = 0; i < 4; i++)
#pragma unroll
                    for (int j = 0; j < 4; j++)
                        ag[i][j] = __builtin_amdgcn_mfma_f32_16x16x32_bf16(af[i], bfr[j], ag[i][j], 0, 0, 0);
            }
            {
                bf16x8 bfr[4];
#pragma unroll
                for (int j = 0; j < 4; j++)
                    bfr[j] = *(const bf16x8*)(Bu + kk * 4096 + (wn + j * 16 + l15) * 32 + quad * 8);
#pragma unroll
                for (int i = 0; i < 4; i++)
#pragma unroll
                    for (int j = 0; j < 4; j++)
                        au[i][j] = __builtin_amdgcn_mfma_f32_16x16x32_bf16(af[i], bfr[j], au[i][j], 0, 0, 0);
            }
        }
        __syncthreads();
    }

#pragma unroll
    for (int i = 0; i < 4; i++) {
        int mb = m0 + wm + i * 16 + quad * 4;
#pragma unroll
        for (int r = 0; r < 4; r++) {
            size_t rowoff = ((size_t)e * CAP + mb + r) * I_DIM;
#pragma unroll
            for (int j = 0; j < 4; j++) {
                int n = n0 + wn + j * 16 + l15;
                float g = ag[i][j][r];
                g = g / (1.f + __expf(-g));          // silu
                float hv = g * au[i][j][r];
                bf16 b = __float2bfloat16(hv);
                hbuf[rowoff + n] = *(us*)&b;
            }
        }
    }
}

// ---------------- down GEMM: hbuf bf16 x Wd(fp32, converted in staging) ----------------
// Same balanced XCD-group schedule (panel = 128 x 1408 fp32 = 0.72 MB).
__global__ __launch_bounds__(256, 3)
void down_gemm(const us* __restrict__ A, const float* __restrict__ W,
               float* __restrict__ dbuf, const int* __restrict__ counts) {
    const int MT = CAP / 128;       // 10
    const int NT = H_DIM / 128;     // 16
    const int d   = blockIdx.x;
    const int xcd = d & 7;
    const int sub = d >> 3;
    const int m0  = (sub % MT) * 128;
    const int g   = (sub / MT) * 8 + xcd;
    const int e   = g / NT;
    const int n0  = (g % NT) * 128;
    if (m0 >= counts[e]) return;

    __shared__ us As[128 * 64];
    __shared__ us Bs[128 * 64];

    const int t  = threadIdx.x;
    const int r0 = t >> 2;
    const int c8 = (t & 3) * 8;

    const us* aP0 = A + ((size_t)e * CAP + m0 + r0) * (size_t)I_DIM + c8;
    const us* aP1 = aP0 + (size_t)64 * I_DIM;
    const float* bP0 = W + ((size_t)e * H_DIM + n0 + r0) * (size_t)I_DIM + c8;
    const float* bP1 = bP0 + (size_t)64 * I_DIM;

    us* lA0 = As + t * 8;  us* lA1 = lA0 + 64 * 32;
    us* lB0 = Bs + t * 8;  us* lB1 = lB0 + 64 * 32;

    const int lane = t & 63;
    const int wave = t >> 6;
    const int wm   = (wave & 1) * 64;
    const int wn   = (wave >> 1) * 64;
    const int l15  = lane & 15;
    const int quad = lane >> 4;

    f32x4 acc[4][4];
#pragma unroll
    for (int i = 0; i < 4; i++)
#pragma unroll
        for (int j = 0; j < 4; j++) acc[i][j] = (f32x4){0.f, 0.f, 0.f, 0.f};

    for (int k = 0; k < I_DIM; k += 64) {
        gld_lds16(aP0,      lA0);
        gld_lds16(aP1,      lA1);
        gld_lds16(aP0 + 32, lA0 + 4096);
        gld_lds16(aP1 + 32, lA1 + 4096);
        stage_f32(bP0,      lB0);
        stage_f32(bP1,      lB1);
        stage_f32(bP0 + 32, lB0 + 4096);
        stage_f32(bP1 + 32, lB1 + 4096);
        aP0 += 64; aP1 += 64; bP0 += 64; bP1 += 64;
        __syncthreads();
#pragma unroll
        for (int kk = 0; kk < 2; kk++) {
            bf16x8 af[4], bfr[4];
#pragma unroll
            for (int i = 0; i < 4; i++)
                af[i] = *(const bf16x8*)(As + kk * 4096 + (wm + i * 16 + l15) * 32 + quad * 8);
#pragma unroll
            for (int j = 0; j < 4; j++)
                bfr[j] = *(const bf16x8*)(Bs + kk * 4096 + (wn + j * 16 + l15) * 32 + quad * 8);
#pragma unroll
            for (int i = 0; i < 4; i++)
#pragma unroll
                for (int j = 0; j < 4; j++)
                    acc[i][j] = __builtin_amdgcn_mfma_f32_16x16x32_bf16(af[i], bfr[j], acc[i][j], 0, 0, 0);
        }
        __syncthreads();
    }

#pragma unroll
    for (int i = 0; i < 4; i++) {
        int mb = m0 + wm + i * 16 + quad * 4;
#pragma unroll
        for (int r = 0; r < 4; r++) {
            float* orow = dbuf + ((size_t)e * CAP + mb + r) * H_DIM + n0 + wn + l15;
#pragma unroll
            for (int j = 0; j < 4; j++)
                orow[j * 16] = acc[i][j][r];
        }
    }
}

// ---------------- final combine: out[tok] = w0*dbuf[p0] + w1*dbuf[p1] ----------------
__global__ void combine_k(const float* __restrict__ dbuf, const int* __restrict__ pos,
                          const float* __restrict__ wz, float* __restrict__ out) {
    int tok = blockIdx.x;
    int off = threadIdx.x * 8;                 // 256 threads x 8 = 2048 = H_DIM
    int p0 = pos[tok * 2], p1 = pos[tok * 2 + 1];
    float w0 = wz[tok * 2], w1 = wz[tok * 2 + 1];
    float4 z = {0.f, 0.f, 0.f, 0.f};
    float4 a0 = z, a1 = z, b0 = z, b1 = z;
    if (p0 >= 0) {
        const float* r = dbuf + (size_t)p0 * H_DIM + off;
        a0 = *(const float4*)r; a1 = *(const float4*)(r + 4);
    }
    if (p1 >= 0) {
        const float* r = dbuf + (size_t)p1 * H_DIM + off;
        b0 = *(const float4*)r; b1 = *(const float4*)(r + 4);
    }
    float4 o0, o1;
    o0.x = w0 * a0.x + w1 * b0.x;  o0.y = w0 * a0.y + w1 * b0.y;
    o0.z = w0 * a0.z + w1 * b0.z;  o0.w = w0 * a0.w + w1 * b0.w;
    o1.x = w0 * a1.x + w1 * b1.x;  o1.y = w0 * a1.y + w1 * b1.y;
    o1.z = w0 * a1.z + w1 * b1.z;  o1.w = w0 * a1.w + w1 * b1.w;
    float* orow = out + (size_t)tok * H_DIM + off;
    *(float4*)orow = o0;
    *(float4*)(orow + 4) = o1;
}

extern "C" void kernel_launch(void* const* d_in, const int* in_sizes, int n_in,
                              void* d_out, int out_size, void* d_ws, size_t ws_size,
                              hipStream_t stream) {
    const float* x  = (const float*)d_in[0];
    const float* Wr = (const float*)d_in[1];
    const float* Wg = (const float*)d_in[2];
    const float* Wu = (const float*)d_in[3];
    const float* Wd = (const float*)d_in[4];
    float* out = (float*)d_out;

    char* p = (char*)d_ws;
    auto alloc = [&](size_t bytes) { char* r = p; p += (bytes + 255) & ~(size_t)255; return r; };
    us* xb   = (us*)alloc((size_t)(N_TOK + 1) * H_DIM * 2);
    us* hbuf = (us*)alloc((size_t)E_NUM * CAP * I_DIM * 2);
    float* dbuf = (float*)alloc((size_t)E_NUM * CAP * H_DIM * 4);
    float* top_val = (float*)alloc((size_t)N_TOK * 2 * 4);
    int*   top_idx = (int*)alloc((size_t)N_TOK * 2 * 4);
    int*   toklist = (int*)alloc((size_t)E_NUM * CAP * 4);
    int*   posm    = (int*)alloc((size_t)N_TOK * 2 * 4);
    float* wz      = (float*)alloc((size_t)N_TOK * 2 * 4);
    int*   counts  = (int*)alloc((size_t)E_NUM * 4);

    hipMemsetAsync(xb + (size_t)N_TOK * H_DIM, 0, H_DIM * 2, stream);

    long nx = (long)N_TOK * H_DIM;
    cvt8<<<dim3((unsigned)((nx / 8 + 255) / 256)), dim3(256), 0, stream>>>(x, xb, nx);

    router_k<<<dim3(N_TOK / 4), dim3(256), 0, stream>>>(x, Wr, top_val, top_idx);
    assign_k<<<dim3(1), dim3(256), 0, stream>>>(top_idx, top_val, toklist, posm, wz, counts);

    // flat grids; see mapping comment in the kernels
    gu_fused<<<dim3((CAP / 128) * (I_DIM / 128) * E_NUM), dim3(256), 0, stream>>>(
        xb, Wg, Wu, hbuf, toklist, counts);

    down_gemm<<<dim3((CAP / 128) * (H_DIM / 128) * E_NUM), dim3(256), 0, stream>>>(
        hbuf, Wd, dbuf, counts);

    combine_k<<<dim3(N_TOK), dim3(256), 0, stream>>>(dbuf, posm, wz, out);
}

// Round 5
// 607.149 us; speedup vs baseline: 1.2050x; 1.2050x over previous
//
#include <hip/hip_runtime.h>
#include <hip/hip_bf16.h>

#define N_TOK 4096
#define H_DIM 2048
#define I_DIM 1408
#define E_NUM 8
#define CAP   1280

typedef __hip_bfloat16 bf16;
typedef unsigned short us;
typedef __bf16 bf16x8 __attribute__((ext_vector_type(8)));
typedef float f32x4 __attribute__((ext_vector_type(4)));

__device__ inline void gld_lds16(const void* g, void* l) {
    __builtin_amdgcn_global_load_lds((const __attribute__((address_space(1))) void*)g,
                                     (__attribute__((address_space(3))) void*)l,
                                     16, 0, 0);
}

// load 8 fp32, convert to bf16x8, store as uint4 (same math as the old cvt kernels)
__device__ inline void cvt_body8(const float* __restrict__ s, us* __restrict__ d, long i) {
    float4 v0 = *(const float4*)(s + i);
    float4 v1 = *(const float4*)(s + i + 4);
    union { us u[8]; uint4 q; } o;
    float f[8] = {v0.x, v0.y, v0.z, v0.w, v1.x, v1.y, v1.z, v1.w};
#pragma unroll
    for (int j = 0; j < 8; j++) {
        bf16 b = __float2bfloat16(f[j]);
        o.u[j] = *(us*)&b;
    }
    *(uint4*)(d + i) = o.q;
}

// ---------------- fused: Wg/Wu fp32->bf16 + x->xb + router ----------------
// blocks 0..511  : grid-stride convert Wg (0-255) / Wu (256-511); block 0 also
//                  zeros the dummy xb row (replaces the hipMemsetAsync dispatch)
// blocks 512..1535: one token per wave -> convert x row to xb AND compute router
//                  logits with the EXACT R1 accumulation order (bitwise-identical
//                  routing decisions).
__global__ void router_cvt(const float* __restrict__ x, const float* __restrict__ Wr,
                           const float* __restrict__ Wg, const float* __restrict__ Wu,
                           us* __restrict__ xb, us* __restrict__ Wgb, us* __restrict__ Wub,
                           float* __restrict__ top_val, int* __restrict__ top_idx) {
    const int bx = blockIdx.x;
    const int t  = threadIdx.x;

    if (bx < 512) {
        const float* s = (bx < 256) ? Wg : Wu;
        us*          d = (bx < 256) ? Wgb : Wub;
        const int   sb = bx & 255;
        const long   n = (long)E_NUM * I_DIM * H_DIM;          // 23,068,672
        for (long i = ((long)sb * 256 + t) * 8; i < n; i += (long)256 * 256 * 8)
            cvt_body8(s, d, i);
        if (bx == 0) {   // zero the dummy token row (tok == N_TOK padding)
            uint4 z = {0u, 0u, 0u, 0u};
            *(uint4*)(xb + (size_t)N_TOK * H_DIM + t * 8) = z;
        }
        return;
    }

    int tok  = (bx - 512) * 4 + (t >> 6);
    int lane = t & 63;
    const float* xr  = x  + (size_t)tok * H_DIM;
    us*          xbr = xb + (size_t)tok * H_DIM;

    // x -> bf16 (row is L1/L2-hot for the router loop below)
#pragma unroll
    for (int q = 0; q < 4; q++) cvt_body8(xr, xbr, q * 512 + lane * 8);

    // router: identical accumulation order to the proven kernel
    float acc[E_NUM];
#pragma unroll
    for (int e = 0; e < E_NUM; e++) acc[e] = 0.f;
    for (int h = lane; h < H_DIM; h += 64) {
        float xv = xr[h];
#pragma unroll
        for (int e = 0; e < E_NUM; e++) acc[e] += xv * Wr[e * H_DIM + h];
    }
#pragma unroll
    for (int e = 0; e < E_NUM; e++) {
#pragma unroll
        for (int off = 32; off > 0; off >>= 1) acc[e] += __shfl_xor(acc[e], off, 64);
    }
    if (lane == 0) {
        float mx = acc[0];
#pragma unroll
        for (int e = 1; e < E_NUM; e++) mx = fmaxf(mx, acc[e]);
        float p[E_NUM], s = 0.f;
#pragma unroll
        for (int e = 0; e < E_NUM; e++) { p[e] = __expf(acc[e] - mx); s += p[e]; }
        float inv = 1.f / s;
#pragma unroll
        for (int e = 0; e < E_NUM; e++) p[e] *= inv;
        int i0 = 0;
#pragma unroll
        for (int e = 1; e < E_NUM; e++) if (p[e] > p[i0]) i0 = e;
        int i1 = -1;
#pragma unroll
        for (int e = 0; e < E_NUM; e++) {
            if (e == i0) continue;
            if (i1 < 0 || p[e] > p[i1]) i1 = e;
        }
        top_idx[tok * 2]     = i0;
        top_idx[tok * 2 + 1] = i1;
        top_val[tok * 2]     = p[i0];
        top_val[tok * 2 + 1] = p[i1];
    }
}

// ---------------- capacity assignment (+ token->slot map for combine) ----------------
__global__ void assign_k(const int* __restrict__ top_idx, const float* __restrict__ top_val,
                         int* __restrict__ toklist, int* __restrict__ pos,
                         float* __restrict__ wz, int* __restrict__ counts) {
    const int T = 256;
    const int CH = (2 * N_TOK) / T; // 32
    int t = threadIdx.x;
    for (int i = t; i < E_NUM * CAP; i += T) toklist[i] = N_TOK;
    __shared__ int cnt[T][E_NUM];
    int local[E_NUM];
#pragma unroll
    for (int e = 0; e < E_NUM; e++) local[e] = 0;
    for (int q = 0; q < CH; q++) {
        int j = t * CH + q;
        int slot = j >> 12;
        int tok  = j & 4095;
        int e = top_idx[tok * 2 + slot];
        local[e]++;
    }
#pragma unroll
    for (int e = 0; e < E_NUM; e++) cnt[t][e] = local[e];
    __syncthreads();
    if (t < E_NUM) {
        int run = 0;
        for (int i = 0; i < T; i++) { int c = cnt[i][t]; cnt[i][t] = run; run += c; }
        counts[t] = run < CAP ? run : CAP;
    }
    __syncthreads();
    int run[E_NUM];
#pragma unroll
    for (int e = 0; e < E_NUM; e++) run[e] = cnt[t][e];
    for (int q = 0; q < CH; q++) {
        int j = t * CH + q;
        int slot = j >> 12;
        int tok  = j & 4095;
        int e = top_idx[tok * 2 + slot];
        int rank = ++run[e];
        if (rank <= CAP) {
            toklist[e * CAP + rank - 1] = tok;
            pos[tok * 2 + slot] = e * CAP + rank - 1;
            wz[tok * 2 + slot]  = top_val[tok * 2 + slot];
        } else {
            pos[tok * 2 + slot] = -1;
            wz[tok * 2 + slot]  = 0.f;
        }
    }
}

// ---------------- fused gate+up GEMM + SwiGLU (+ Wd conversion side-blocks) ----------------
// Blocks 0..255: grid-stride convert Wd fp32->bf16 (overlaps with the GEMM,
// which only uses ~40% of HBM BW). Blocks 256..1135: the proven R1 GEMM,
// m fastest (id%10), then n, then e. MUST stay at 2 blocks/CU: dual 4x4
// accumulators (128 regs) + staging exceed the 3-wave/SIMD budget (R4's
// "WRITE_SIZE=245MB" was accumulator spill traffic at launch_bounds(...,3)).
__global__ __launch_bounds__(256, 2)
void gu_fused(const us* __restrict__ A, const us* __restrict__ Wg,
              const us* __restrict__ Wu, us* __restrict__ hbuf,
              const int* __restrict__ toklist, const int* __restrict__ counts,
              const float* __restrict__ Wd, us* __restrict__ Wdb) {
    const int t = threadIdx.x;
    if (blockIdx.x < 256) {
        const long n = (long)E_NUM * H_DIM * I_DIM;
        for (long i = ((long)blockIdx.x * 256 + t) * 8; i < n; i += (long)256 * 256 * 8)
            cvt_body8(Wd, Wdb, i);
        return;
    }
    const int id = blockIdx.x - 256;
    const int m0 = (id % 10) * 128;
    const int n0 = ((id / 10) % 11) * 128;
    const int e  = id / 110;
    if (m0 >= counts[e]) return;

    __shared__ us As[128 * 64];   // two sub-buffers of [128][32]
    __shared__ us Bg[128 * 64];
    __shared__ us Bu[128 * 64];

    const int r0 = t >> 2;          // 0..63
    const int c8 = (t & 3) * 8;     // 0/8/16/24

    int tok0 = toklist[e * CAP + m0 + r0];
    int tok1 = toklist[e * CAP + m0 + r0 + 64];
    const us* aP0 = A + (size_t)tok0 * H_DIM + c8;
    const us* aP1 = A + (size_t)tok1 * H_DIM + c8;
    const us* gP0 = Wg + ((size_t)e * I_DIM + n0 + r0) * H_DIM + c8;
    const us* gP1 = gP0 + (size_t)64 * H_DIM;
    const us* uP0 = Wu + ((size_t)e * I_DIM + n0 + r0) * H_DIM + c8;
    const us* uP1 = uP0 + (size_t)64 * H_DIM;

    us* lA0 = As + t * 8;  us* lA1 = lA0 + 64 * 32;   // sub0 rows 0-63 / 64-127
    us* lG0 = Bg + t * 8;  us* lG1 = lG0 + 64 * 32;
    us* lU0 = Bu + t * 8;  us* lU1 = lU0 + 64 * 32;

    const int lane = t & 63;
    const int wave = t >> 6;
    const int wm   = (wave & 1) * 64;
    const int wn   = (wave >> 1) * 64;
    const int l15  = lane & 15;
    const int quad = lane >> 4;

    f32x4 ag[4][4], au[4][4];
#pragma unroll
    for (int i = 0; i < 4; i++)
#pragma unroll
        for (int j = 0; j < 4; j++) {
            ag[i][j] = (f32x4){0.f, 0.f, 0.f, 0.f};
            au[i][j] = (f32x4){0.f, 0.f, 0.f, 0.f};
        }

    for (int k = 0; k < H_DIM; k += 64) {
        gld_lds16(aP0,      lA0);
        gld_lds16(aP1,      lA1);
        gld_lds16(aP0 + 32, lA0 + 4096);
        gld_lds16(aP1 + 32, lA1 + 4096);
        gld_lds16(gP0,      lG0);
        gld_lds16(gP1,      lG1);
        gld_lds16(gP0 + 32, lG0 + 4096);
        gld_lds16(gP1 + 32, lG1 + 4096);
        gld_lds16(uP0,      lU0);
        gld_lds16(uP1,      lU1);
        gld_lds16(uP0 + 32, lU0 + 4096);
        gld_lds16(uP1 + 32, lU1 + 4096);
        aP0 += 64; aP1 += 64; gP0 += 64; gP1 += 64; uP0 += 64; uP1 += 64;
        __syncthreads();
#pragma unroll
        for (int kk = 0; kk < 2; kk++) {
            bf16x8 af[4];
#pragma unroll
            for (int i = 0; i < 4; i++)
                af[i] = *(const bf16x8*)(As + kk * 4096 + (wm + i * 16 + l15) * 32 + quad * 8);
            {
                bf16x8 bfr[4];
#pragma unroll
                for (int j = 0; j < 4; j++)
                    bfr[j] = *(const bf16x8*)(Bg + kk * 4096 + (wn + j * 16 + l15) * 32 + quad * 8);
#pragma unroll
                for (int i = 0; i < 4; i++)
#pragma unroll
                    for (int j = 0; j < 4; j++)
                        ag[i][j] = __builtin_amdgcn_mfma_f32_16x16x32_bf16(af[i], bfr[j], ag[i][j], 0, 0, 0);
            }
            {
                bf16x8 bfr[4];
#pragma unroll
                for (int j = 0; j < 4; j++)
                    bfr[j] = *(const bf16x8*)(Bu + kk * 4096 + (wn + j * 16 + l15) * 32 + quad * 8);
#pragma unroll
                for (int i = 0; i < 4; i++)
#pragma unroll
                    for (int j = 0; j < 4; j++)
                        au[i][j] = __builtin_amdgcn_mfma_f32_16x16x32_bf16(af[i], bfr[j], au[i][j], 0, 0, 0);
            }
        }
        __syncthreads();
    }

#pragma unroll
    for (int i = 0; i < 4; i++) {
        int mb = m0 + wm + i * 16 + quad * 4;
#pragma unroll
        for (int r = 0; r < 4; r++) {
            size_t rowoff = ((size_t)e * CAP + mb + r) * I_DIM;
#pragma unroll
            for (int j = 0; j < 4; j++) {
                int n = n0 + wn + j * 16 + l15;
                float g = ag[i][j][r];
                g = g / (1.f + __expf(-g));          // silu
                float hv = g * au[i][j][r];
                bf16 b = __float2bfloat16(hv);
                hbuf[rowoff + n] = *(us*)&b;
            }
        }
    }
}

// ---------------- down GEMM, no atomics: raw rows -> dbuf ----------------
__global__ __launch_bounds__(256, 3)
void down_gemm(const us* __restrict__ A, const us* __restrict__ W,
               float* __restrict__ dbuf, const int* __restrict__ counts) {
    const int e  = blockIdx.z;
    const int m0 = blockIdx.x * 128;
    const int n0 = blockIdx.y * 128;
    if (m0 >= counts[e]) return;

    __shared__ us As[128 * 64];
    __shared__ us Bs[128 * 64];

    const int t  = threadIdx.x;
    const int r0 = t >> 2;
    const int c8 = (t & 3) * 8;

    const us* aP0 = A + ((size_t)e * CAP + m0 + r0) * (size_t)I_DIM + c8;
    const us* aP1 = aP0 + (size_t)64 * I_DIM;
    const us* bP0 = W + ((size_t)e * H_DIM + n0 + r0) * (size_t)I_DIM + c8;
    const us* bP1 = bP0 + (size_t)64 * I_DIM;

    us* lA0 = As + t * 8;  us* lA1 = lA0 + 64 * 32;
    us* lB0 = Bs + t * 8;  us* lB1 = lB0 + 64 * 32;

    const int lane = t & 63;
    const int wave = t >> 6;
    const int wm   = (wave & 1) * 64;
    const int wn   = (wave >> 1) * 64;
    const int l15  = lane & 15;
    const int quad = lane >> 4;

    f32x4 acc[4][4];
#pragma unroll
    for (int i = 0; i < 4; i++)
#pragma unroll
        for (int j = 0; j < 4; j++) acc[i][j] = (f32x4){0.f, 0.f, 0.f, 0.f};

    for (int k = 0; k < I_DIM; k += 64) {
        gld_lds16(aP0,      lA0);
        gld_lds16(aP1,      lA1);
        gld_lds16(aP0 + 32, lA0 + 4096);
        gld_lds16(aP1 + 32, lA1 + 4096);
        gld_lds16(bP0,      lB0);
        gld_lds16(bP1,      lB1);
        gld_lds16(bP0 + 32, lB0 + 4096);
        gld_lds16(bP1 + 32, lB1 + 4096);
        aP0 += 64; aP1 += 64; bP0 += 64; bP1 += 64;
        __syncthreads();
#pragma unroll
        for (int kk = 0; kk < 2; kk++) {
            bf16x8 af[4], bfr[4];
#pragma unroll
            for (int i = 0; i < 4; i++)
                af[i] = *(const bf16x8*)(As + kk * 4096 + (wm + i * 16 + l15) * 32 + quad * 8);
#pragma unroll
            for (int j = 0; j < 4; j++)
                bfr[j] = *(const bf16x8*)(Bs + kk * 4096 + (wn + j * 16 + l15) * 32 + quad * 8);
#pragma unroll
            for (int i = 0; i < 4; i++)
#pragma unroll
                for (int j = 0; j < 4; j++)
                    acc[i][j] = __builtin_amdgcn_mfma_f32_16x16x32_bf16(af[i], bfr[j], acc[i][j], 0, 0, 0);
        }
        __syncthreads();
    }

#pragma unroll
    for (int i = 0; i < 4; i++) {
        int mb = m0 + wm + i * 16 + quad * 4;
#pragma unroll
        for (int r = 0; r < 4; r++) {
            float* orow = dbuf + ((size_t)e * CAP + mb + r) * H_DIM + n0 + wn + l15;
#pragma unroll
            for (int j = 0; j < 4; j++)
                orow[j * 16] = acc[i][j][r];
        }
    }
}

// ---------------- final combine: out[tok] = w0*dbuf[p0] + w1*dbuf[p1] ----------------
__global__ void combine_k(const float* __restrict__ dbuf, const int* __restrict__ pos,
                          const float* __restrict__ wz, float* __restrict__ out) {
    int tok = blockIdx.x;
    int off = threadIdx.x * 8;                 // 256 threads x 8 = 2048 = H_DIM
    int p0 = pos[tok * 2], p1 = pos[tok * 2 + 1];
    float w0 = wz[tok * 2], w1 = wz[tok * 2 + 1];
    float4 z = {0.f, 0.f, 0.f, 0.f};
    float4 a0 = z, a1 = z, b0 = z, b1 = z;
    if (p0 >= 0) {
        const float* r = dbuf + (size_t)p0 * H_DIM + off;
        a0 = *(const float4*)r; a1 = *(const float4*)(r + 4);
    }
    if (p1 >= 0) {
        const float* r = dbuf + (size_t)p1 * H_DIM + off;
        b0 = *(const float4*)r; b1 = *(const float4*)(r + 4);
    }
    float4 o0, o1;
    o0.x = w0 * a0.x + w1 * b0.x;  o0.y = w0 * a0.y + w1 * b0.y;
    o0.z = w0 * a0.z + w1 * b0.z;  o0.w = w0 * a0.w + w1 * b0.w;
    o1.x = w0 * a1.x + w1 * b1.x;  o1.y = w0 * a1.y + w1 * b1.y;
    o1.z = w0 * a1.z + w1 * b1.z;  o1.w = w0 * a1.w + w1 * b1.w;
    float* orow = out + (size_t)tok * H_DIM + off;
    *(float4*)orow = o0;
    *(float4*)(orow + 4) = o1;
}

extern "C" void kernel_launch(void* const* d_in, const int* in_sizes, int n_in,
                              void* d_out, int out_size, void* d_ws, size_t ws_size,
                              hipStream_t stream) {
    const float* x  = (const float*)d_in[0];
    const float* Wr = (const float*)d_in[1];
    const float* Wg = (const float*)d_in[2];
    const float* Wu = (const float*)d_in[3];
    const float* Wd = (const float*)d_in[4];
    float* out = (float*)d_out;

    char* p = (char*)d_ws;
    auto alloc = [&](size_t bytes) { char* r = p; p += (bytes + 255) & ~(size_t)255; return r; };
    us* xb   = (us*)alloc((size_t)(N_TOK + 1) * H_DIM * 2);
    us* Wgb  = (us*)alloc((size_t)E_NUM * I_DIM * H_DIM * 2);
    us* Wub  = (us*)alloc((size_t)E_NUM * I_DIM * H_DIM * 2);
    us* Wdb  = (us*)alloc((size_t)E_NUM * H_DIM * I_DIM * 2);
    us* hbuf = (us*)alloc((size_t)E_NUM * CAP * I_DIM * 2);
    float* top_val = (float*)alloc((size_t)N_TOK * 2 * 4);
    int*   top_idx = (int*)alloc((size_t)N_TOK * 2 * 4);
    int*   toklist = (int*)alloc((size_t)E_NUM * CAP * 4);
    int*   posm    = (int*)alloc((size_t)N_TOK * 2 * 4);
    float* wz      = (float*)alloc((size_t)N_TOK * 2 * 4);
    int*   counts  = (int*)alloc((size_t)E_NUM * 4);
    // dbuf (E*CAP*H fp32 = 83.9 MB) aliases Wgb+Wub (92.3 MB contiguous, dead
    // after gu_fused; stream order guarantees safety).
    float* dbuf = (float*)Wgb;

    // 1) Wg/Wu convert + x convert + router (one kernel, fully co-resident)
    router_cvt<<<dim3(512 + N_TOK / 4), dim3(256), 0, stream>>>(
        x, Wr, Wg, Wu, xb, Wgb, Wub, top_val, top_idx);

    // 2) capacity assignment
    assign_k<<<dim3(1), dim3(256), 0, stream>>>(top_idx, top_val, toklist, posm, wz, counts);

    // 3) gate+up GEMM (+ Wd conversion overlapped in leading blocks)
    gu_fused<<<dim3(256 + (CAP / 128) * (I_DIM / 128) * E_NUM), dim3(256), 0, stream>>>(
        xb, Wgb, Wub, hbuf, toklist, counts, Wd, Wdb);

    // 4) down GEMM -> raw per-slot rows
    dim3 g2(CAP / 128, H_DIM / 128, E_NUM);   // 10 x 16 x 8, m fastest
    down_gemm<<<g2, dim3(256), 0, stream>>>(hbuf, Wdb, dbuf, counts);

    // 5) weighted combine
    combine_k<<<dim3(N_TOK), dim3(256), 0, stream>>>(dbuf, posm, wz, out);
}